// Round 3
// baseline (245.052 us; speedup 1.0000x reference)
//
#include <hip/hip_runtime.h>
#include <cstdint>

// Problem constants: B=32, C=256, P=32, H=W=56
#define B_    32
#define C_    256
#define P_    32
#define HW_   3136
#define NSTEP 98          // k-steps of 32 (98*32 = 3136)

typedef __attribute__((ext_vector_type(8))) short  short8;   // 8 x bf16 (MFMA A/B frag)
typedef __attribute__((ext_vector_type(4))) float  floatx4;  // MFMA C/D frag + native f32x4

__device__ __forceinline__ unsigned short f2bf(float f) {
    // round-to-nearest-even f32 -> bf16
    union { float f; unsigned u; } v; v.f = f;
    unsigned r = v.u + 0x7fffu + ((v.u >> 16) & 1u);
    return (unsigned short)(r >> 16);
}

// ---------------------------------------------------------------------------
// Kernel 1: wpart[b,p,hw] = bf16( part[b,p,hw] * sigmoid(sum_p' part*w + b) )
// (unchanged)
// ---------------------------------------------------------------------------
__global__ __launch_bounds__(64) void wprep_kernel(
    const float* __restrict__ part, const float* __restrict__ conv_w,
    const float* __restrict__ conv_b, unsigned short* __restrict__ wpart)
{
    const int HW4 = HW_ / 4;                          // 784
    int i4 = blockIdx.x * 64 + threadIdx.x;           // over B*HW/4 = 25088
    if (i4 >= B_ * HW4) return;
    int b  = i4 / HW4;
    int hw = (i4 - b * HW4) * 4;

    const float* pb = part + (size_t)b * P_ * HW_ + hw;
    float bias = conv_b[0];
    float4 z = make_float4(bias, bias, bias, bias);
#pragma unroll
    for (int p = 0; p < P_; ++p) {
        float w = conv_w[p];
        float4 v = *(const float4*)(pb + (size_t)p * HW_);
        z.x += v.x * w; z.y += v.y * w; z.z += v.z * w; z.w += v.w * w;
    }
    float4 a;
    a.x = 1.0f / (1.0f + __expf(-z.x));
    a.y = 1.0f / (1.0f + __expf(-z.y));
    a.z = 1.0f / (1.0f + __expf(-z.z));
    a.w = 1.0f / (1.0f + __expf(-z.w));

    unsigned short* ob = wpart + (size_t)b * P_ * HW_ + hw;
#pragma unroll
    for (int p = 0; p < P_; ++p) {
        float4 v = *(const float4*)(pb + (size_t)p * HW_);   // L1/L2-hot reload
        ushort4 o;
        o.x = f2bf(v.x * a.x); o.y = f2bf(v.y * a.y);
        o.z = f2bf(v.z * a.z); o.w = f2bf(v.w * a.w);
        *(ushort4*)(ob + (size_t)p * HW_) = o;
    }
}

// ---------------------------------------------------------------------------
// Kernel 2: DIAGNOSTIC build of the v3 streaming bf16-MFMA GEMM.
//   feats[b,p,c] = sum_k wpart[b,p,k] * x[b,c,k]
// Identical math/structure to v3, but the whole body repeats `nrep` times
// (runtime arg => no cross-rep CSE). Each rep recomputes the IDENTICAL
// output (idempotent overwrite) -> correctness preserved, dispatch time
// ~ nrep * gemm, forcing the gemm into rocprof's top-5 so we finally get
// its dur / hbm_gbps / MfmaUtil / VALUBusy / FETCH_SIZE.
//   nrep=3 expected: dur 55-70us if gemm is at its ~18us HBM floor
//   (=> revert + ROOFLINE next round), 120-150us if it is ~45us
//   (=> real headroom; counters name the pipe).
// ---------------------------------------------------------------------------
__global__ __launch_bounds__(512, 4) void gemm_stream3r(
    const float* __restrict__ x,              // [B,C,HW] fp32
    const unsigned short* __restrict__ wpart, // [B,P,HW] bf16
    float* __restrict__ out,                  // [B, P*C]
    int nrep)
{
    __shared__ float red[8][512];             // 16 KB

    // bijective XCD-chunked swizzle (512 % 8 == 0)
    const int orig = blockIdx.x;              // hw round-robins orig%8 -> XCD
    const int swz  = (orig & 7) * 64 + (orig >> 3);
    const int ct   = swz & 15;                // c-chunk 0..15
    const int b    = swz >> 4;                // batch: XCD x gets b in [4x,4x+4)
    const int c0   = ct * 16;

    const int tid  = threadIdx.x;
    const int wv   = tid >> 6;                // 0..7 : k-slice
    const int lane = tid & 63;
    const int qd   = lane >> 4;               // quad 0..3 -> k-offset qd*8
    const int r15  = lane & 15;               // row within 16

    const int t0 = wv * NSTEP / 8;
    const int t1 = (wv + 1) * NSTEP / 8;

    // lane-fixed base pointers (k advances by 32 floats per step)
    const float*          xr  = x + (size_t)b * C_ * HW_ + (size_t)(c0 + r15) * HW_ + qd * 8;
    const unsigned short* ar0 = wpart + (size_t)b * P_ * HW_ + (size_t)r15 * HW_ + qd * 8;
    const unsigned short* ar1 = ar0 + (size_t)16 * HW_;

    for (int rep = 0; rep < nrep; ++rep) {
        floatx4 acc0 = (floatx4)0.0f;             // p rows 0..15
        floatx4 acc1 = (floatx4)0.0f;             // p rows 16..31

#pragma unroll 4
        for (int t = t0; t < t1; ++t) {
            const int kb = t * 32;
            // A fragments: 16B contiguous per lane, L2-hot (XCD-resident wpart)
            short8 a0 = *(const short8*)(ar0 + kb);
            short8 a1 = *(const short8*)(ar1 + kb);
            // B fragments: 8 consecutive k floats of this lane's x-row, streamed
            floatx4 x0 = __builtin_nontemporal_load((const floatx4*)(xr + kb));
            floatx4 x1 = __builtin_nontemporal_load((const floatx4*)(xr + kb) + 1);
            short8 b0;
            b0[0] = (short)f2bf(x0[0]); b0[1] = (short)f2bf(x0[1]);
            b0[2] = (short)f2bf(x0[2]); b0[3] = (short)f2bf(x0[3]);
            b0[4] = (short)f2bf(x1[0]); b0[5] = (short)f2bf(x1[1]);
            b0[6] = (short)f2bf(x1[2]); b0[7] = (short)f2bf(x1[3]);

            acc0 = __builtin_amdgcn_mfma_f32_16x16x32_bf16(a0, b0, acc0, 0, 0, 0);
            acc1 = __builtin_amdgcn_mfma_f32_16x16x32_bf16(a1, b0, acc1, 0, 0, 0);
        }

        // ---- reduction across the 8 k-slice waves ----
        // D layout: p = (acc sel)*16 + qd*4 + rg, c-col = r15 ; idx = p*16 + c
#pragma unroll
        for (int rg = 0; rg < 4; ++rg) {
            red[wv][(qd * 4 + rg) * 16 + r15]      = acc0[rg];
            red[wv][(16 + qd * 4 + rg) * 16 + r15] = acc1[rg];
        }
        __syncthreads();

        float s = 0.0f;
#pragma unroll
        for (int w = 0; w < 8; ++w) s += red[w][tid];
        const int p  = tid >> 4;                  // 0..31
        const int cl = tid & 15;                  // 0..15
        __builtin_nontemporal_store(s, &out[(size_t)b * (P_ * C_) + p * C_ + c0 + cl]);

        __syncthreads();   // WAR: red[][] reused next rep
    }
}

extern "C" void kernel_launch(void* const* d_in, const int* in_sizes, int n_in,
                              void* d_out, int out_size, void* d_ws, size_t ws_size,
                              hipStream_t stream) {
    const float* x      = (const float*)d_in[0];
    const float* part   = (const float*)d_in[1];
    const float* conv_w = (const float*)d_in[2];
    const float* conv_b = (const float*)d_in[3];
    unsigned short* wpart = (unsigned short*)d_ws;   // [B,P,HW] bf16 = 6.4 MB

    wprep_kernel<<<dim3((B_ * (HW_ / 4) + 63) / 64), dim3(64), 0, stream>>>(
        part, conv_w, conv_b, wpart);

    gemm_stream3r<<<dim3(512), dim3(512), 0, stream>>>(
        x, wpart, (float*)d_out, 3);
}

// Round 4
// 172.236 us; speedup vs baseline: 1.4228x; 1.4228x over previous
//
#include <hip/hip_runtime.h>
#include <cstdint>

// Problem constants: B=32, C=256, P=32, H=W=56
#define B_    32
#define C_    256
#define P_    32
#define HW_   3136
#define KT    256         // k-tile in floats (8 MFMA k-steps of 32)
#define NT    13          // ceil(3136/256); tile 12 covers k 3072..3135 (+pad)

typedef __attribute__((ext_vector_type(8))) short  short8;   // 8 x bf16 (MFMA A/B frag)
typedef __attribute__((ext_vector_type(4))) float  floatx4;  // MFMA C/D frag + native f32x4

__device__ __forceinline__ unsigned short f2bf(float f) {
    // round-to-nearest-even f32 -> bf16
    union { float f; unsigned u; } v; v.f = f;
    unsigned r = v.u + 0x7fffu + ((v.u >> 16) & 1u);
    return (unsigned short)(r >> 16);
}

// async global->LDS, 16B per lane; LDS dest = wave-uniform base + lane*16,
// global src is PER-LANE (m104/m173 semantics).
__device__ __forceinline__ void glds16(const unsigned short* g, unsigned short* l) {
    __builtin_amdgcn_global_load_lds(
        (const __attribute__((address_space(1))) unsigned int*)(g),
        (__attribute__((address_space(3))) unsigned int*)(l),
        16, 0, 0);
}

// ---------------------------------------------------------------------------
// Kernel 1: wpart[b,p,hw] = bf16( part[b,p,hw] * sigmoid(sum_p' part*w + b) )
// (unchanged)
// ---------------------------------------------------------------------------
__global__ __launch_bounds__(64) void wprep_kernel(
    const float* __restrict__ part, const float* __restrict__ conv_w,
    const float* __restrict__ conv_b, unsigned short* __restrict__ wpart)
{
    const int HW4 = HW_ / 4;                          // 784
    int i4 = blockIdx.x * 64 + threadIdx.x;           // over B*HW/4 = 25088
    if (i4 >= B_ * HW4) return;
    int b  = i4 / HW4;
    int hw = (i4 - b * HW4) * 4;

    const float* pb = part + (size_t)b * P_ * HW_ + hw;
    float bias = conv_b[0];
    float4 z = make_float4(bias, bias, bias, bias);
#pragma unroll
    for (int p = 0; p < P_; ++p) {
        float w = conv_w[p];
        float4 v = *(const float4*)(pb + (size_t)p * HW_);
        z.x += v.x * w; z.y += v.y * w; z.z += v.z * w; z.w += v.w * w;
    }
    float4 a;
    a.x = 1.0f / (1.0f + __expf(-z.x));
    a.y = 1.0f / (1.0f + __expf(-z.y));
    a.z = 1.0f / (1.0f + __expf(-z.z));
    a.w = 1.0f / (1.0f + __expf(-z.w));

    unsigned short* ob = wpart + (size_t)b * P_ * HW_ + hw;
#pragma unroll
    for (int p = 0; p < P_; ++p) {
        float4 v = *(const float4*)(pb + (size_t)p * HW_);   // L1/L2-hot reload
        ushort4 o;
        o.x = f2bf(v.x * a.x); o.y = f2bf(v.y * a.y);
        o.z = f2bf(v.z * a.z); o.w = f2bf(v.w * a.w);
        *(ushort4*)(ob + (size_t)p * HW_) = o;
    }
}

// ---------------------------------------------------------------------------
// Kernel 2: LDS-staged bf16-MFMA GEMM, v4.
//   feats[b,p,c] = sum_k wpart[b,p,k] * x[b,c,k]
// v3 diagnosis (nrep=3 rocprof): 33us/pass, hbm 17.5%, MfmaUtil 1.9%,
// VALUBusy 7.3%, warm==cold -> TA/address-divergence bound (~100 cyc per
// 16-row-scattered VMEM instr). v4 makes every GLOBAL access wave-contiguous
// (1KB/instr) and takes the fragment scatter through LDS:
//   per 256-float k-tile: 8 waves stage x[16c][256k] (coalesced float4 ->
//   f2bf -> ds_write_b64) and wpart[32p][256k] (global_load_lds_dwordx4,
//   per-lane src spanning 2 rows, linear LDS dest); wave wv computes k-step
//   wv: 3x ds_read_b128 + 2 MFMA. Double-buffered, 1 barrier/tile.
// No LDS swizzle: regime is HBM/latency-bound, LDS reads off critical path.
// LDS: xb 16KB + wb 32KB = 48KB (red aliases wb[0]) -> 2 blocks/CU, 16 wv/CU.
// Tail tile: x predicated-zero, wpart src clamped (finite * 0 = 0).
// ---------------------------------------------------------------------------
__global__ __launch_bounds__(512, 4) void gemm_lds4(
    const float* __restrict__ x,              // [B,C,HW] fp32
    const unsigned short* __restrict__ wpart, // [B,P,HW] bf16
    float* __restrict__ out)                  // [B, P*C]
{
    __shared__ unsigned short xb[2][16][KT];  // 16 KB
    __shared__ unsigned short wb[2][32][KT];  // 32 KB (reused as red[] in epilogue)

    // bijective XCD-chunked swizzle (512 = 8*64): XCD x owns b in [4x,4x+4)
    const int orig = blockIdx.x;
    const int swzb = (orig & 7) * 64 + (orig >> 3);
    const int ct   = swzb & 15;               // c-chunk 0..15
    const int b    = swzb >> 4;               // batch
    const int c0   = ct * 16;

    const int tid  = threadIdx.x;
    const int wv   = tid >> 6;                // wave 0..7
    const int lane = tid & 63;
    const int qd   = lane >> 4;               // quad 0..3
    const int r15  = lane & 15;               // row within 16
    const int l5   = lane & 31;               // lane within half-wave
    const int hh   = lane >> 5;               // half-wave 0/1

    // staging bases:
    // x: wave wv stages c-rows {wv*2, wv*2+1}; lane -> row wv*2+hh
    const float* xg = x + (size_t)b * C_ * HW_ + (size_t)(c0 + wv * 2 + hh) * HW_;
    // wpart: wave wv stages p-rows {wv*4 .. wv*4+3}; instr j covers rows wv*4+2j+{0,1}
    const unsigned short* wg0 = wpart + (size_t)b * P_ * HW_ + (size_t)(wv * 4 + hh) * HW_;
    const unsigned short* wg1 = wg0 + (size_t)2 * HW_;

    floatx4 acc0 = (floatx4)0.0f;             // p rows 0..15
    floatx4 acc1 = (floatx4)0.0f;             // p rows 16..31

    // ---- prologue: stage tile 0 into buffer 0 ----
    {
        const int gb0 = l5 * 16;                                  // kb=0, in-bounds
        glds16((const unsigned short*)((const char*)wg0 + gb0), &wb[0][wv * 4][0]);
        glds16((const unsigned short*)((const char*)wg1 + gb0), &wb[0][wv * 4 + 2][0]);
        const int f0 = l5 * 4, f1 = f0 + 128;                     // both valid at tile 0
        floatx4 xv0 = __builtin_nontemporal_load((const floatx4*)(xg + f0));
        floatx4 xv1 = __builtin_nontemporal_load((const floatx4*)(xg + f1));
        ushort4 o0, o1;
        o0.x = f2bf(xv0[0]); o0.y = f2bf(xv0[1]); o0.z = f2bf(xv0[2]); o0.w = f2bf(xv0[3]);
        o1.x = f2bf(xv1[0]); o1.y = f2bf(xv1[1]); o1.z = f2bf(xv1[2]); o1.w = f2bf(xv1[3]);
        char* xrow = (char*)&xb[0][wv * 2 + hh][0];
        *(ushort4*)(xrow + l5 * 8)       = o0;
        *(ushort4*)(xrow + l5 * 8 + 256) = o1;
    }
    __syncthreads();   // compiler drains vmcnt/lgkmcnt before s_barrier

    for (int t = 0; t < NT; ++t) {
        const int cur = t & 1, nxt = cur ^ 1;
        const bool st = (t + 1) < NT;
        floatx4 xv0 = (floatx4)0.0f, xv1 = (floatx4)0.0f;

        if (st) {
            const int kb = (t + 1) * KT;
            // x loads (issue early; HBM latency hides under compute+barrier)
            const int f0 = kb + l5 * 4, f1 = f0 + 128;
            if (f0 + 4 <= HW_) xv0 = __builtin_nontemporal_load((const floatx4*)(xg + f0));
            if (f1 + 4 <= HW_) xv1 = __builtin_nontemporal_load((const floatx4*)(xg + f1));
            // wpart async global->LDS (clamped in-bounds for tail tile)
            int gb = kb * 2 + l5 * 16;
            if (gb > HW_ * 2 - 16) gb = HW_ * 2 - 16;
            glds16((const unsigned short*)((const char*)wg0 + gb), &wb[nxt][wv * 4][0]);
            glds16((const unsigned short*)((const char*)wg1 + gb), &wb[nxt][wv * 4 + 2][0]);
        }

        // ---- compute k-step wv of tile t ----
        const int eo = wv * 32 + qd * 8;      // element offset within row
        short8 a0 = *(const short8*)&wb[cur][r15][eo];
        short8 a1 = *(const short8*)&wb[cur][r15 + 16][eo];
        short8 bf = *(const short8*)&xb[cur][r15][eo];
        acc0 = __builtin_amdgcn_mfma_f32_16x16x32_bf16(a0, bf, acc0, 0, 0, 0);
        acc1 = __builtin_amdgcn_mfma_f32_16x16x32_bf16(a1, bf, acc1, 0, 0, 0);

        if (st) {
            ushort4 o0, o1;
            o0.x = f2bf(xv0[0]); o0.y = f2bf(xv0[1]); o0.z = f2bf(xv0[2]); o0.w = f2bf(xv0[3]);
            o1.x = f2bf(xv1[0]); o1.y = f2bf(xv1[1]); o1.z = f2bf(xv1[2]); o1.w = f2bf(xv1[3]);
            char* xrow = (char*)&xb[nxt][wv * 2 + hh][0];
            *(ushort4*)(xrow + l5 * 8)       = o0;
            *(ushort4*)(xrow + l5 * 8 + 256) = o1;
        }
        __syncthreads();   // tile t+1 fully in LDS after this
    }

    // ---- reduction across the 8 k-step waves (red aliases wb[0], 16KB) ----
    float* red = (float*)&wb[0][0][0];
#pragma unroll
    for (int rg = 0; rg < 4; ++rg) {
        red[wv * 512 + (qd * 4 + rg) * 16 + r15]        = acc0[rg];
        red[wv * 512 + (16 + qd * 4 + rg) * 16 + r15]   = acc1[rg];
    }
    __syncthreads();

    float s = 0.0f;
#pragma unroll
    for (int w = 0; w < 8; ++w) s += red[w * 512 + tid];
    const int p  = tid >> 4;                  // 0..31
    const int cl = tid & 15;                  // 0..15
    __builtin_nontemporal_store(s, &out[(size_t)b * (P_ * C_) + p * C_ + c0 + cl]);
}

extern "C" void kernel_launch(void* const* d_in, const int* in_sizes, int n_in,
                              void* d_out, int out_size, void* d_ws, size_t ws_size,
                              hipStream_t stream) {
    const float* x      = (const float*)d_in[0];
    const float* part   = (const float*)d_in[1];
    const float* conv_w = (const float*)d_in[2];
    const float* conv_b = (const float*)d_in[3];
    unsigned short* wpart = (unsigned short*)d_ws;   // [B,P,HW] bf16 = 6.4 MB

    wprep_kernel<<<dim3((B_ * (HW_ / 4) + 63) / 64), dim3(64), 0, stream>>>(
        part, conv_w, conv_b, wpart);

    gemm_lds4<<<dim3(512), dim3(512), 0, stream>>>(
        x, wpart, (float*)d_out);
}

// Round 5
// 171.642 us; speedup vs baseline: 1.4277x; 1.0035x over previous
//
#include <hip/hip_runtime.h>
#include <cstdint>

// Problem constants: B=32, C=256, P=32, H=W=56
#define B_    32
#define C_    256
#define P_    32
#define HW_   3136
#define KT    256         // k-tile in floats (8 MFMA k-steps of 32)
#define NT    13          // ceil(3136/256); tile 12 covers k 3072..3135 (+pad)

typedef __attribute__((ext_vector_type(8))) short  short8;   // 8 x bf16 (MFMA A/B frag)
typedef __attribute__((ext_vector_type(4))) float  floatx4;  // MFMA C/D frag + native f32x4

__device__ __forceinline__ unsigned short f2bf(float f) {
    // round-to-nearest-even f32 -> bf16
    union { float f; unsigned u; } v; v.f = f;
    unsigned r = v.u + 0x7fffu + ((v.u >> 16) & 1u);
    return (unsigned short)(r >> 16);
}

// async global->LDS, 16B per lane; LDS dest = wave-uniform base + lane*16,
// global src is PER-LANE (m104/m173 semantics).
__device__ __forceinline__ void glds16(const unsigned short* g, unsigned short* l) {
    __builtin_amdgcn_global_load_lds(
        (const __attribute__((address_space(1))) unsigned int*)(g),
        (__attribute__((address_space(3))) unsigned int*)(l),
        16, 0, 0);
}

// ---------------------------------------------------------------------------
// Kernel 1: wpart[b,p,hw] = bf16( part[b,p,hw] * sigmoid(sum_p' part*w + b) )
// (unchanged)
// ---------------------------------------------------------------------------
__global__ __launch_bounds__(64) void wprep_kernel(
    const float* __restrict__ part, const float* __restrict__ conv_w,
    const float* __restrict__ conv_b, unsigned short* __restrict__ wpart)
{
    const int HW4 = HW_ / 4;                          // 784
    int i4 = blockIdx.x * 64 + threadIdx.x;           // over B*HW/4 = 25088
    if (i4 >= B_ * HW4) return;
    int b  = i4 / HW4;
    int hw = (i4 - b * HW4) * 4;

    const float* pb = part + (size_t)b * P_ * HW_ + hw;
    float bias = conv_b[0];
    float4 z = make_float4(bias, bias, bias, bias);
#pragma unroll
    for (int p = 0; p < P_; ++p) {
        float w = conv_w[p];
        float4 v = *(const float4*)(pb + (size_t)p * HW_);
        z.x += v.x * w; z.y += v.y * w; z.z += v.z * w; z.w += v.w * w;
    }
    float4 a;
    a.x = 1.0f / (1.0f + __expf(-z.x));
    a.y = 1.0f / (1.0f + __expf(-z.y));
    a.z = 1.0f / (1.0f + __expf(-z.z));
    a.w = 1.0f / (1.0f + __expf(-z.w));

    unsigned short* ob = wpart + (size_t)b * P_ * HW_ + hw;
#pragma unroll
    for (int p = 0; p < P_; ++p) {
        float4 v = *(const float4*)(pb + (size_t)p * HW_);   // L1/L2-hot reload
        ushort4 o;
        o.x = f2bf(v.x * a.x); o.y = f2bf(v.y * a.y);
        o.z = f2bf(v.z * a.z); o.w = f2bf(v.w * a.w);
        *(ushort4*)(ob + (size_t)p * HW_) = o;
    }
}

// ---------------------------------------------------------------------------
// Kernel 2: LDS-staged bf16-MFMA GEMM, v5 = v4 + T4 counted-vmcnt pipeline.
//   feats[b,p,c] = sum_k wpart[b,p,k] * x[b,c,k]
// v4 (172us total) removed the TA-divergence bottleneck but keeps one
// __syncthreads() per tile -> hipcc drains vmcnt(0) 13x + serial prologue.
// v5: ring-of-3 LDS buffers (72KB, still 2 blocks/CU); iter t issues
// stage(t+2) (2x glds16 + 2x clamped x loads, ALWAYS exactly 4 vmem ops),
// then s_waitcnt vmcnt(4) -> drains exactly tile t+1's staging (glds are
// oldest in batch), ds_write x(t+1), compute tile t, lgkmcnt(0) +
// raw s_barrier (loads for t+2 stay in flight ACROSS the barrier).
// Slot-race audit: slot s x-written iter s-1, glds-written iter s-2,
// read iter s; 3 slots => every write >=1 barrier after last read. Tail
// x loads are clamped+select-zero (not predicated) so vmcnt counts are
// wave-uniform and exact.
// ---------------------------------------------------------------------------
__global__ __launch_bounds__(512, 4) void gemm_lds5(
    const float* __restrict__ x,              // [B,C,HW] fp32
    const unsigned short* __restrict__ wpart, // [B,P,HW] bf16
    float* __restrict__ out)                  // [B, P*C]
{
    __shared__ unsigned short xb[3][16][KT];  // 24 KB
    __shared__ unsigned short wb[3][32][KT];  // 48 KB (wb[0] reused as red[])

    // bijective XCD-chunked swizzle (512 = 8*64): XCD x owns b in [4x,4x+4)
    const int orig = blockIdx.x;
    const int swzb = (orig & 7) * 64 + (orig >> 3);
    const int ct   = swzb & 15;               // c-chunk 0..15
    const int b    = swzb >> 4;               // batch
    const int c0   = ct * 16;

    const int tid  = threadIdx.x;
    const int wv   = tid >> 6;                // wave 0..7
    const int lane = tid & 63;
    const int qd   = lane >> 4;               // quad 0..3
    const int r15  = lane & 15;               // row within 16
    const int l5   = lane & 31;               // lane within half-wave
    const int hh   = lane >> 5;               // half-wave 0/1

    // staging bases (identical to v4's verified layout):
    const float* xg = x + (size_t)b * C_ * HW_ + (size_t)(c0 + wv * 2 + hh) * HW_;
    const unsigned short* wg0 = wpart + (size_t)b * P_ * HW_ + (size_t)(wv * 4 + hh) * HW_;
    const unsigned short* wg1 = wg0 + (size_t)2 * HW_;

    floatx4 acc0 = (floatx4)0.0f;             // p rows 0..15
    floatx4 acc1 = (floatx4)0.0f;             // p rows 16..31

    // --- staging helpers (issue exactly 2 glds + 2 vmem loads each) ---
    auto stage_w = [&](int slot, int t) {
        int gb = t * KT * 2 + l5 * 16;
        if (gb > HW_ * 2 - 16) gb = HW_ * 2 - 16;             // tail clamp (finite*0=0)
        glds16((const unsigned short*)((const char*)wg0 + gb), &wb[slot][wv * 4][0]);
        glds16((const unsigned short*)((const char*)wg1 + gb), &wb[slot][wv * 4 + 2][0]);
    };
    auto load_x = [&](int t, floatx4& v0, floatx4& v1) {
        const int kb = t * KT;
        int f0 = kb + l5 * 4, f1 = f0 + 128;
        int a0 = f0 > HW_ - 4 ? HW_ - 4 : f0;                 // clamped: load ALWAYS issues
        int a1 = f1 > HW_ - 4 ? HW_ - 4 : f1;
        floatx4 t0 = __builtin_nontemporal_load((const floatx4*)(xg + a0));
        floatx4 t1 = __builtin_nontemporal_load((const floatx4*)(xg + a1));
        v0 = (f0 + 4 <= HW_) ? t0 : (floatx4)0.0f;            // select-zero OOB
        v1 = (f1 + 4 <= HW_) ? t1 : (floatx4)0.0f;
    };
    auto write_x = [&](int slot, floatx4 v0, floatx4 v1) {
        ushort4 o0, o1;
        o0.x = f2bf(v0[0]); o0.y = f2bf(v0[1]); o0.z = f2bf(v0[2]); o0.w = f2bf(v0[3]);
        o1.x = f2bf(v1[0]); o1.y = f2bf(v1[1]); o1.z = f2bf(v1[2]); o1.w = f2bf(v1[3]);
        char* xrow = (char*)&xb[slot][wv * 2 + hh][0];
        *(ushort4*)(xrow + l5 * 8)       = o0;
        *(ushort4*)(xrow + l5 * 8 + 256) = o1;
    };

    // ---- prologue: issue tiles 0 and 1; commit tile 0 ----
    floatx4 t0a, t0b, xA0, xA1, xB0, xB1;
    stage_w(0, 0);
    load_x(0, t0a, t0b);          // tile0: 2 glds + 2 loads (oldest 4)
    stage_w(1, 1);
    load_x(1, xA0, xA1);          // tile1: next 4 (stay in flight)
    asm volatile("s_waitcnt vmcnt(4)" ::: "memory");          // tile0 done
    __builtin_amdgcn_sched_barrier(0);
    write_x(0, t0a, t0b);
    asm volatile("s_waitcnt lgkmcnt(0)" ::: "memory");        // ds_writes visible
    __builtin_amdgcn_sched_barrier(0);
    __builtin_amdgcn_s_barrier();

    int sc = 0, sn = 1, sp = 2;   // slots of t, t+1, t+2
    for (int t = 0; t < NT; ++t) {
        if (t + 2 < NT) {
            stage_w(sp, t + 2);                               // exactly 4 new vmem ops
            load_x(t + 2, xB0, xB1);
            asm volatile("s_waitcnt vmcnt(4)" ::: "memory");  // tile t+1 staging done
        } else {
            asm volatile("s_waitcnt vmcnt(0)" ::: "memory");  // tail: drain all
        }
        __builtin_amdgcn_sched_barrier(0);

        if (t + 1 < NT) write_x(sn, xA0, xA1);                // commit x(t+1) to LDS

        // ---- compute k-step wv of tile t (frags identical to v4) ----
        const int eo = wv * 32 + qd * 8;
        short8 a0 = *(const short8*)&wb[sc][r15][eo];
        short8 a1 = *(const short8*)&wb[sc][r15 + 16][eo];
        short8 bf = *(const short8*)&xb[sc][r15][eo];
        acc0 = __builtin_amdgcn_mfma_f32_16x16x32_bf16(a0, bf, acc0, 0, 0, 0);
        acc1 = __builtin_amdgcn_mfma_f32_16x16x32_bf16(a1, bf, acc1, 0, 0, 0);

        xA0 = xB0; xA1 = xB1;                                 // rotate pending x regs
        int tmp = sc; sc = sn; sn = sp; sp = tmp;             // rotate slots

        asm volatile("s_waitcnt lgkmcnt(0)" ::: "memory");    // ds_writes committed
        __builtin_amdgcn_sched_barrier(0);
        __builtin_amdgcn_s_barrier();                         // t+2 loads stay in flight
    }

    // ---- reduction across the 8 k-step waves (red aliases wb[0], 16KB) ----
    float* red = (float*)&wb[0][0][0];
#pragma unroll
    for (int rg = 0; rg < 4; ++rg) {
        red[wv * 512 + (qd * 4 + rg) * 16 + r15]      = acc0[rg];
        red[wv * 512 + (16 + qd * 4 + rg) * 16 + r15] = acc1[rg];
    }
    __syncthreads();

    float s = 0.0f;
#pragma unroll
    for (int w = 0; w < 8; ++w) s += red[w * 512 + tid];
    const int p  = tid >> 4;                  // 0..31
    const int cl = tid & 15;                  // 0..15
    __builtin_nontemporal_store(s, &out[(size_t)b * (P_ * C_) + p * C_ + c0 + cl]);
}

extern "C" void kernel_launch(void* const* d_in, const int* in_sizes, int n_in,
                              void* d_out, int out_size, void* d_ws, size_t ws_size,
                              hipStream_t stream) {
    const float* x      = (const float*)d_in[0];
    const float* part   = (const float*)d_in[1];
    const float* conv_w = (const float*)d_in[2];
    const float* conv_b = (const float*)d_in[3];
    unsigned short* wpart = (unsigned short*)d_ws;   // [B,P,HW] bf16 = 6.4 MB

    wprep_kernel<<<dim3((B_ * (HW_ / 4) + 63) / 64), dim3(64), 0, stream>>>(
        part, conv_w, conv_b, wpart);

    gemm_lds5<<<dim3(512), dim3(512), 0, stream>>>(
        x, wpart, (float*)d_out);
}